// Round 7
// baseline (861.762 us; speedup 1.0000x reference)
//
#include <hip/hip_runtime.h>
#include <hip/hip_bf16.h>

typedef __attribute__((ext_vector_type(8))) short short8;
typedef __attribute__((ext_vector_type(4))) float f32x4;

#define NTOK 8192
#define HCH  2048
#define DDIM 128

__device__ __forceinline__ unsigned short f2bf(float f) {
    __hip_bfloat16 h = __float2bfloat16(f);   // RNE
    return *reinterpret_cast<unsigned short*>(&h);
}

// ---------------------------------------------------------------------------
// Kernel 0: runtime dtype detection (proven).
// flags[0]: 1 -> X/W fp32, 0 -> bf16.
// flags[1]: mask mode: 0=u32 word, 1=byte, 2=u16, 3=packed bits.
// ---------------------------------------------------------------------------
__global__ void detect_kernel(const unsigned int* __restrict__ X,
                              const unsigned int* __restrict__ M,
                              int* __restrict__ flags)
{
    if (threadIdx.x == 0 && blockIdx.x == 0) {
        int hits = 0;
        for (int i = 0; i < 64; i++) {
            unsigned int e = (X[i] >> 7) & 0xFF;
            if (e >= 110 && e <= 140) hits++;
        }
        flags[0] = (hits < 32) ? 1 : 0;

        bool allw = true, allh = true, allb = true;
        for (int i = 0; i < 1024; i++) {
            unsigned int u = M[i];
            if (!(u == 0u || u == 1u || u == 0x3F800000u)) allw = false;
            unsigned int h0 = u & 0xFFFFu, h1 = u >> 16;
            bool o0 = (h0 == 0u || h0 == 0x3F80u || h0 == 0x3C00u || h0 == 1u);
            bool o1 = (h1 == 0u || h1 == 0x3F80u || h1 == 0x3C00u || h1 == 1u);
            if (!(o0 && o1)) allh = false;
            unsigned int b0 = u & 0xFF, b1 = (u >> 8) & 0xFF,
                         b2 = (u >> 16) & 0xFF, b3 = u >> 24;
            if (b0 > 1u || b1 > 1u || b2 > 1u || b3 > 1u) allb = false;
        }
        flags[1] = allw ? 0 : (allb ? 1 : (allh ? 2 : 3));
    }
}

// ---------------------------------------------------------------------------
// Kernel 0b: W -> bf16 (copy if already bf16).
// ---------------------------------------------------------------------------
__global__ __launch_bounds__(256) void conv_w(
    const void* __restrict__ Wv, const int* __restrict__ flags,
    unsigned short* __restrict__ Wbf)
{
    int t = blockIdx.x * 256 + threadIdx.x;
    size_t off = (size_t)t * 8;
    if (flags[0] != 0) {
        const float* Wf = (const float*)Wv;
        float4 a = *reinterpret_cast<const float4*>(Wf + off);
        float4 b = *reinterpret_cast<const float4*>(Wf + off + 4);
        unsigned short o[8] = { f2bf(a.x), f2bf(a.y), f2bf(a.z), f2bf(a.w),
                                f2bf(b.x), f2bf(b.y), f2bf(b.z), f2bf(b.w) };
        *reinterpret_cast<uint4*>(Wbf + off) = *reinterpret_cast<uint4*>(o);
    } else {
        *reinterpret_cast<uint4*>(Wbf + off) =
            *reinterpret_cast<const uint4*>((const unsigned short*)Wv + off);
    }
}

// ---------------------------------------------------------------------------
// Kernel 0c: mask -> 1 bit/elem via wave ballot.  Mp[row][tile] u64, bit j =
// mask[row][tile*64+j].  Wave reads 64 consecutive elems (coalesced), ballots.
// grid 1024 x 256 (4 waves); wave gw handles rows [2gw, 2gw+2), 256 tiles.
// ---------------------------------------------------------------------------
__global__ __launch_bounds__(256) void mask_pack(
    const void* __restrict__ maskv, const int* __restrict__ flags,
    unsigned long long* __restrict__ Mp)
{
    const int lane = threadIdx.x & 63;
    const int gw = blockIdx.x * 4 + (threadIdx.x >> 6);
    const int mmode = flags[1];
#pragma unroll 4
    for (int s = 0; s < 256; s++) {
        int row = gw * 2 + (s >> 7);
        int tile = s & 127;
        size_t mi = (size_t)row * NTOK + tile * 64 + lane;
        bool pred;
        if (mmode == 0)      pred = ((const unsigned int*)maskv)[mi] != 0u;
        else if (mmode == 1) pred = ((const unsigned char*)maskv)[mi] != 0;
        else if (mmode == 2) pred = ((const unsigned short*)maskv)[mi] != 0;
        else pred = ((((const unsigned char*)maskv)[mi >> 3] >> (mi & 7)) & 1) != 0;
        unsigned long long b = __ballot(pred);
        if (lane == 0) Mp[(size_t)row * 128 + tile] = b;
    }
}

// ---------------------------------------------------------------------------
// Kernel 1: QKV projection (unchanged from r6).
// ---------------------------------------------------------------------------
__global__ __launch_bounds__(256) void qkv_gemm(
    const void* __restrict__ Xv, const unsigned short* __restrict__ Wbf,
    const int* __restrict__ flags,
    unsigned short* __restrict__ Qb, unsigned short* __restrict__ Kb,
    unsigned short* __restrict__ Vb)
{
    __shared__ unsigned short Wsm[128 * 64];
    __shared__ unsigned short Xsm[32 * 64];
    const int tid  = threadIdx.x;
    const int lane = tid & 63, w = tid >> 6;
    const int c = lane & 15, g = lane >> 4;
    const int q0 = blockIdx.x * 32;
    const int n0 = blockIdx.y * 128;
    const bool f32in = (flags[0] != 0);
    const float*          Xf = (const float*)Xv;
    const unsigned short* Xb = (const unsigned short*)Xv;

    f32x4 acc[4];
#pragma unroll
    for (int i = 0; i < 4; i++) acc[i] = (f32x4){0.f, 0.f, 0.f, 0.f};

    const int xrow = tid >> 3, xc8 = tid & 7;
    const int arow = (w & 1) * 16 + c;

    for (int kk = 0; kk < HCH; kk += 64) {
        __syncthreads();
#pragma unroll
        for (int i = 0; i < 4; i++) {
            int cid = tid + 256 * i;
            int n = cid >> 3, c8 = cid & 7;
            uint4 v = *reinterpret_cast<const uint4*>(Wbf + (size_t)(n0 + n) * HCH + kk + c8 * 8);
            *reinterpret_cast<uint4*>(&Wsm[(n * 8 + (c8 ^ (n & 7))) * 8]) = v;
        }
        {
            unsigned short o[8];
            if (f32in) {
                const float* p = Xf + (size_t)(q0 + xrow) * HCH + kk + xc8 * 8;
                float4 a = *reinterpret_cast<const float4*>(p);
                float4 b = *reinterpret_cast<const float4*>(p + 4);
                o[0]=f2bf(a.x); o[1]=f2bf(a.y); o[2]=f2bf(a.z); o[3]=f2bf(a.w);
                o[4]=f2bf(b.x); o[5]=f2bf(b.y); o[6]=f2bf(b.z); o[7]=f2bf(b.w);
            } else {
                *reinterpret_cast<uint4*>(o) =
                    *reinterpret_cast<const uint4*>(Xb + (size_t)(q0 + xrow) * HCH + kk + xc8 * 8);
            }
            *reinterpret_cast<uint4*>(&Xsm[(xrow * 8 + (xc8 ^ (xrow & 7))) * 8]) =
                *reinterpret_cast<uint4*>(o);
        }
        __syncthreads();
#pragma unroll
        for (int ks = 0; ks < 2; ks++) {
            short8 af = *reinterpret_cast<const short8*>(
                &Xsm[(arow * 8 + ((ks * 4 + g) ^ (c & 7))) * 8]);
#pragma unroll
            for (int nt = 0; nt < 4; nt++) {
                int n = (w >> 1) * 64 + nt * 16 + c;
                short8 bf = *reinterpret_cast<const short8*>(
                    &Wsm[(n * 8 + ((ks * 4 + g) ^ (c & 7))) * 8]);
                acc[nt] = __builtin_amdgcn_mfma_f32_16x16x32_bf16(af, bf, acc[nt], 0, 0, 0);
            }
        }
    }
    unsigned short* dst = (blockIdx.y == 0) ? Qb : (blockIdx.y == 1) ? Kb : Vb;
#pragma unroll
    for (int nt = 0; nt < 4; nt++) {
        int n = (w >> 1) * 64 + nt * 16 + c;
#pragma unroll
        for (int r = 0; r < 4; r++) {
            int rr = q0 + (w & 1) * 16 + g * 4 + r;
            dst[(size_t)rr * DDIM + n] = f2bf(acc[nt][r]);
        }
    }
}

// ---------------------------------------------------------------------------
// Kernel 2: V [8192][128] -> VT [128][8192]  (unchanged)
// ---------------------------------------------------------------------------
__global__ __launch_bounds__(256) void vtrans(
    const unsigned short* __restrict__ V, unsigned short* __restrict__ VT)
{
    __shared__ unsigned short T[32 * 33];
    const int t = threadIdx.x;
    const int k0 = blockIdx.x * 32, d0 = blockIdx.y * 32;
    {
        int key = t >> 3, dq = (t & 7) * 4;
        ushort4 v = *reinterpret_cast<const ushort4*>(V + (size_t)(k0 + key) * DDIM + d0 + dq);
        T[(dq + 0) * 33 + key] = v.x;
        T[(dq + 1) * 33 + key] = v.y;
        T[(dq + 2) * 33 + key] = v.z;
        T[(dq + 3) * 33 + key] = v.w;
    }
    __syncthreads();
    {
        int d = t >> 3, kq = (t & 7) * 4;
        ushort4 o;
        o.x = T[d * 33 + kq + 0]; o.y = T[d * 33 + kq + 1];
        o.z = T[d * 33 + kq + 2]; o.w = T[d * 33 + kq + 3];
        *reinterpret_cast<ushort4*>(VT + (size_t)(d0 + d) * NTOK + k0 + kq) = o;
    }
}

// ---------------------------------------------------------------------------
// Kernel 3: flash partials v3. Packed-bit mask (4 broadcast u64 loads/iter).
// grid (128, nsplit). Swizzled LDS; fixed m=0 softmax; l via P*ones MFMA.
// ---------------------------------------------------------------------------
__global__ __launch_bounds__(256, 4) void attn_part(
    const unsigned short* __restrict__ Qb, const unsigned short* __restrict__ Kb,
    const unsigned short* __restrict__ VT, const unsigned long long* __restrict__ Mp,
    _Float16* __restrict__ Opart, float* __restrict__ lpart, int kps)
{
    __shared__ unsigned short Ksm[64 * 128];
    __shared__ unsigned short Vsm[128 * 64];
    __shared__ unsigned short Psm[4 * 16 * 64];
    const int tid  = threadIdx.x;
    const int lane = tid & 63, w = tid >> 6;
    const int c = lane & 15, g = lane >> 4;
    const int q0 = blockIdx.x * 64;
    const int split = blockIdx.y;
    const int kbase = split * kps;
    const int niter = kps >> 6;
    const int tb0 = kbase >> 6;
    unsigned short* Pw = &Psm[w * 16 * 64];

    short8 qf[4];
#pragma unroll
    for (int ks = 0; ks < 4; ks++)
        qf[ks] = *reinterpret_cast<const short8*>(Qb + (size_t)(q0 + w * 16 + c) * DDIM + ks * 32 + g * 8);

    short8 ones;
#pragma unroll
    for (int i = 0; i < 8; i++) ones[i] = (short)0x3F80;   // bf16 1.0

    f32x4 accO[8];
#pragma unroll
    for (int i = 0; i < 8; i++) accO[i] = (f32x4){0.f, 0.f, 0.f, 0.f};
    f32x4 accL = (f32x4){0.f, 0.f, 0.f, 0.f};

    unsigned long long mp[4], mpn[4];
#pragma unroll
    for (int r = 0; r < 4; r++)
        mp[r] = Mp[(size_t)(q0 + w * 16 + g * 4 + r) * 128 + tb0];

    for (int t = 0; t < niter; t++) {
        const int k0 = kbase + t * 64;
        __syncthreads();                              // prior-iter LDS reads done
#pragma unroll
        for (int i = 0; i < 4; i++) {                 // stage K tile [64][128]
            int cid = tid + 256 * i;
            int rowk = cid >> 4, c16 = cid & 15;
            uint4 v = *reinterpret_cast<const uint4*>(Kb + (size_t)(k0 + rowk) * DDIM + c16 * 8);
            *reinterpret_cast<uint4*>(&Ksm[(rowk * 16 + (c16 ^ (rowk & 15))) * 8]) = v;
        }
#pragma unroll
        for (int i = 0; i < 4; i++) {                 // stage VT tile [128][64]
            int cid = tid + 256 * i;
            int d = cid >> 3, c8 = cid & 7;
            uint4 v = *reinterpret_cast<const uint4*>(VT + (size_t)d * NTOK + k0 + c8 * 8);
            *reinterpret_cast<uint4*>(&Vsm[(d * 8 + (c8 ^ (d & 7))) * 8]) = v;
        }
        if (t + 1 < niter) {                          // prefetch next mask bits
#pragma unroll
            for (int r = 0; r < 4; r++)
                mpn[r] = Mp[(size_t)(q0 + w * 16 + g * 4 + r) * 128 + tb0 + t + 1];
        }
        __syncthreads();

        // ---- S = Q K^T ----
        f32x4 sacc[4];
#pragma unroll
        for (int nt = 0; nt < 4; nt++) {
            sacc[nt] = (f32x4){0.f, 0.f, 0.f, 0.f};
#pragma unroll
            for (int ks = 0; ks < 4; ks++) {
                short8 bf = *reinterpret_cast<const short8*>(
                    &Ksm[((nt * 16 + c) * 16 + ((ks * 4 + g) ^ c)) * 8]);
                sacc[nt] = __builtin_amdgcn_mfma_f32_16x16x32_bf16(qf[ks], bf, sacc[nt], 0, 0, 0);
            }
        }

        // ---- mask bits + exp (fixed m=0; logits bounded) -> P in LDS ----
#pragma unroll
        for (int nt = 0; nt < 4; nt++)
#pragma unroll
            for (int r = 0; r < 4; r++) {
                bool mv = (mp[r] >> (nt * 16 + c)) & 1ull;
                float p = mv ? 0.f : __expf(sacc[nt][r] * (1.0f / 128.0f));
                int row = g * 4 + r;
                Pw[(row * 8 + ((nt * 2 + (c >> 3)) ^ (row & 7))) * 8 + (c & 7)] = f2bf(p);
            }
#pragma unroll
        for (int r = 0; r < 4; r++) mp[r] = mpn[r];

        // ---- O += P V ; l += P * ones ----
#pragma unroll
        for (int ks2 = 0; ks2 < 2; ks2++) {
            short8 af = *reinterpret_cast<const short8*>(
                &Pw[(c * 8 + ((ks2 * 4 + g) ^ (c & 7))) * 8]);
            accL = __builtin_amdgcn_mfma_f32_16x16x32_bf16(af, ones, accL, 0, 0, 0);
#pragma unroll
            for (int dt = 0; dt < 8; dt++) {
                short8 bfv = *reinterpret_cast<const short8*>(
                    &Vsm[((dt * 16 + c) * 8 + ((ks2 * 4 + g) ^ (c & 7))) * 8]);
                accO[dt] = __builtin_amdgcn_mfma_f32_16x16x32_bf16(af, bfv, accO[dt], 0, 0, 0);
            }
        }
    }

    _Float16* Op = Opart + (size_t)split * NTOK * DDIM;
#pragma unroll
    for (int nt = 0; nt < 8; nt++)
#pragma unroll
        for (int r = 0; r < 4; r++)
            Op[(size_t)(q0 + w * 16 + g * 4 + r) * DDIM + nt * 16 + c] = (_Float16)accO[nt][r];
    if (c == 0) {
#pragma unroll
        for (int r = 0; r < 4; r++)
            lpart[(size_t)split * NTOK + q0 + w * 16 + g * 4 + r] = accL[r];
    }
}

// ---------------------------------------------------------------------------
// Kernel 4: combine nsplit key-splits -> fp32 out.
// ---------------------------------------------------------------------------
__global__ __launch_bounds__(256) void combine(
    const _Float16* __restrict__ Opart, const float* __restrict__ lpart,
    float* __restrict__ out, int nsplit)
{
    int idx = blockIdx.x * 256 + threadIdx.x;
    int row = idx >> 7;
    const size_t S = (size_t)NTOK * DDIM;
    float den = 0.f, num = 0.f;
    for (int s = 0; s < nsplit; s++) {
        den += lpart[(size_t)s * NTOK + row];
        num += (float)Opart[(size_t)s * S + idx];
    }
    out[idx] = (den > 0.f) ? (num / den) : 0.f;
}

// ---------------------------------------------------------------------------
extern "C" void kernel_launch(void* const* d_in, const int* in_sizes, int n_in,
                              void* d_out, int out_size, void* d_ws, size_t ws_size,
                              hipStream_t stream)
{
    const void* X = d_in[0]; const void* mask = d_in[1]; const void* W = d_in[2];
    {
        const void* x_ = nullptr; const void* m_ = nullptr; const void* w_ = nullptr;
        for (int i = 0; i < n_in; i++) {
            if (in_sizes[i] == 16777216) x_ = d_in[i];
            else if (in_sizes[i] == 67108864) m_ = d_in[i];
            else if (in_sizes[i] == 786432) w_ = d_in[i];
        }
        if (x_ && m_ && w_) { X = x_; mask = m_; W = w_; }
    }
    float* out = (float*)d_out;                 // fp32 [8192][128]

    // nsplit by workspace budget: 8 needs ~30.3 MB, 4 needs ~22.3 MB (proven).
    const int nsplit = (ws_size >= (33ull << 20)) ? 8 : 4;
    const int kps = NTOK / nsplit;

    char* ws = (char*)d_ws;
    unsigned short* Qb  = (unsigned short*)(ws);                    // 0..2 MB
    unsigned short* Kb  = (unsigned short*)(ws + (2ull << 20));     // 2..4
    unsigned short* VT  = (unsigned short*)(ws + (4ull << 20));     // 4..6
    unsigned long long* Mpk = (unsigned long long*)(ws + (6ull << 20)); // 6..14
    _Float16*       Opart = (_Float16*)(ws + (14ull << 20));        // 14..14+2*nsplit
    unsigned short* Wbf = (unsigned short*)(ws + (14ull << 20));    // aliases Opart (dead before attn)
    unsigned short* Vb  = (unsigned short*)(ws + (14ull << 20) + (1536ull << 10)); // +1.5..+3.5 (dead after vtrans)
    float*          lpart = (float*)(ws + (14ull << 20) + ((size_t)nsplit << 21)); // after Opart
    int*            flags = (int*)((char*)lpart + (128ull << 10));

    detect_kernel<<<1, 64, 0, stream>>>((const unsigned int*)X, (const unsigned int*)mask, flags);
    conv_w<<<dim3(384), 256, 0, stream>>>(W, flags, Wbf);
    mask_pack<<<dim3(1024), 256, 0, stream>>>(mask, flags, Mpk);
    qkv_gemm<<<dim3(256, 3), 256, 0, stream>>>(X, Wbf, flags, Qb, Kb, Vb);
    vtrans<<<dim3(256, 4), 256, 0, stream>>>(Vb, VT);
    attn_part<<<dim3(128, nsplit), 256, 0, stream>>>(Qb, Kb, VT, Mpk, Opart, lpart, kps);
    combine<<<dim3(4096), 256, 0, stream>>>(Opart, lpart, out, nsplit);
}

// Round 8
// 619.608 us; speedup vs baseline: 1.3908x; 1.3908x over previous
//
#include <hip/hip_runtime.h>
#include <hip/hip_bf16.h>

typedef __attribute__((ext_vector_type(8))) short short8;
typedef __attribute__((ext_vector_type(4))) float f32x4;

#define NTOK 8192
#define HCH  2048
#define DDIM 128

__device__ __forceinline__ unsigned short f2bf(float f) {
    __hip_bfloat16 h = __float2bfloat16(f);   // RNE
    return *reinterpret_cast<unsigned short*>(&h);
}

// ---------------------------------------------------------------------------
// Kernel 0: runtime dtype detection v2 — one wave, parallel (old version was
// 1 thread x 1088 serial HBM loads ~= 0.4 ms, the hidden cost of every round).
// flags[0]: 1 -> X/W fp32, 0 -> bf16.
// flags[1]: mask mode: 0=u32 word, 1=byte, 2=u16, 3=packed bits.
// ---------------------------------------------------------------------------
__global__ void detect_kernel(const unsigned int* __restrict__ X,
                              const unsigned int* __restrict__ M,
                              int* __restrict__ flags)
{
    const int lane = threadIdx.x & 63;
    unsigned int e = (X[lane] >> 7) & 0xFF;
    unsigned long long hb = __ballot(e >= 110 && e <= 140);

    bool w_ok = true, h_ok = true, b_ok = true;
#pragma unroll
    for (int i = 0; i < 16; i++) {
        unsigned int u = M[lane + 64 * i];
        if (!(u == 0u || u == 1u || u == 0x3F800000u)) w_ok = false;
        unsigned int h0 = u & 0xFFFFu, h1 = u >> 16;
        bool o0 = (h0 == 0u || h0 == 0x3F80u || h0 == 0x3C00u || h0 == 1u);
        bool o1 = (h1 == 0u || h1 == 0x3F80u || h1 == 0x3C00u || h1 == 1u);
        if (!(o0 && o1)) h_ok = false;
        unsigned int b0 = u & 0xFF, b1 = (u >> 8) & 0xFF,
                     b2 = (u >> 16) & 0xFF, b3 = u >> 24;
        if (b0 > 1u || b1 > 1u || b2 > 1u || b3 > 1u) b_ok = false;
    }
    bool allw = __all(w_ok), allh = __all(h_ok), allb = __all(b_ok);
    if (lane == 0) {
        flags[0] = (__popcll(hb) < 32) ? 1 : 0;
        flags[1] = allw ? 0 : (allb ? 1 : (allh ? 2 : 3));
    }
}

// ---------------------------------------------------------------------------
// Kernel 0b: W -> bf16 (copy if already bf16).
// ---------------------------------------------------------------------------
__global__ __launch_bounds__(256) void conv_w(
    const void* __restrict__ Wv, const int* __restrict__ flags,
    unsigned short* __restrict__ Wbf)
{
    int t = blockIdx.x * 256 + threadIdx.x;
    size_t off = (size_t)t * 8;
    if (flags[0] != 0) {
        const float* Wf = (const float*)Wv;
        float4 a = *reinterpret_cast<const float4*>(Wf + off);
        float4 b = *reinterpret_cast<const float4*>(Wf + off + 4);
        unsigned short o[8] = { f2bf(a.x), f2bf(a.y), f2bf(a.z), f2bf(a.w),
                                f2bf(b.x), f2bf(b.y), f2bf(b.z), f2bf(b.w) };
        *reinterpret_cast<uint4*>(Wbf + off) = *reinterpret_cast<uint4*>(o);
    } else {
        *reinterpret_cast<uint4*>(Wbf + off) =
            *reinterpret_cast<const uint4*>((const unsigned short*)Wv + off);
    }
}

// ---------------------------------------------------------------------------
// Kernel 0c: mask -> 1 bit/elem, v2 (no ballot; ILP + coalesced).
// Thread -> one output byte = 8 consecutive elements. Word mode: 2 x uint4
// (32 B contiguous per lane, 2 KB per wave). Bit k of byte b = elem 8b+k
// (LSB-first) -> attn's little-endian u64 read sees bit j = elem 64t+j.
// grid 2048 x 256, grid-stride 16 iters.
// ---------------------------------------------------------------------------
__global__ __launch_bounds__(256) void mask_pack(
    const void* __restrict__ maskv, const int* __restrict__ flags,
    unsigned char* __restrict__ Mp)
{
    const int mmode = flags[1];
    const int NB = NTOK * (NTOK / 8);          // 8 Mi bytes
    int t0 = blockIdx.x * 256 + threadIdx.x;
    for (int b = t0; b < NB; b += 2048 * 256) {
        unsigned int byte = 0;
        if (mmode == 0) {
            const uint4* p = reinterpret_cast<const uint4*>(
                (const unsigned int*)maskv + (size_t)b * 8);
            uint4 a = p[0], c = p[1];
            byte = (a.x != 0u) | ((a.y != 0u) << 1) | ((a.z != 0u) << 2) | ((a.w != 0u) << 3)
                 | ((c.x != 0u) << 4) | ((c.y != 0u) << 5) | ((c.z != 0u) << 6) | ((c.w != 0u) << 7);
        } else if (mmode == 1) {
            unsigned long long v = *reinterpret_cast<const unsigned long long*>(
                (const unsigned char*)maskv + (size_t)b * 8);
#pragma unroll
            for (int k = 0; k < 8; k++)
                byte |= (((v >> (8 * k)) & 0xFFull) != 0ull) << k;
        } else if (mmode == 2) {
            uint4 a = *reinterpret_cast<const uint4*>(
                (const unsigned short*)maskv + (size_t)b * 8);
            byte = ((a.x & 0xFFFFu) != 0u) | ((a.x >> 16 != 0u) << 1)
                 | (((a.y & 0xFFFFu) != 0u) << 2) | ((a.y >> 16 != 0u) << 3)
                 | (((a.z & 0xFFFFu) != 0u) << 4) | ((a.z >> 16 != 0u) << 5)
                 | (((a.w & 0xFFFFu) != 0u) << 6) | ((a.w >> 16 != 0u) << 7);
        } else {
            byte = ((const unsigned char*)maskv)[b];
        }
        Mp[b] = (unsigned char)byte;
    }
}

// ---------------------------------------------------------------------------
// Kernel 1: QKV projection (unchanged from r6).
// ---------------------------------------------------------------------------
__global__ __launch_bounds__(256) void qkv_gemm(
    const void* __restrict__ Xv, const unsigned short* __restrict__ Wbf,
    const int* __restrict__ flags,
    unsigned short* __restrict__ Qb, unsigned short* __restrict__ Kb,
    unsigned short* __restrict__ Vb)
{
    __shared__ unsigned short Wsm[128 * 64];
    __shared__ unsigned short Xsm[32 * 64];
    const int tid  = threadIdx.x;
    const int lane = tid & 63, w = tid >> 6;
    const int c = lane & 15, g = lane >> 4;
    const int q0 = blockIdx.x * 32;
    const int n0 = blockIdx.y * 128;
    const bool f32in = (flags[0] != 0);
    const float*          Xf = (const float*)Xv;
    const unsigned short* Xb = (const unsigned short*)Xv;

    f32x4 acc[4];
#pragma unroll
    for (int i = 0; i < 4; i++) acc[i] = (f32x4){0.f, 0.f, 0.f, 0.f};

    const int xrow = tid >> 3, xc8 = tid & 7;
    const int arow = (w & 1) * 16 + c;

    for (int kk = 0; kk < HCH; kk += 64) {
        __syncthreads();
#pragma unroll
        for (int i = 0; i < 4; i++) {
            int cid = tid + 256 * i;
            int n = cid >> 3, c8 = cid & 7;
            uint4 v = *reinterpret_cast<const uint4*>(Wbf + (size_t)(n0 + n) * HCH + kk + c8 * 8);
            *reinterpret_cast<uint4*>(&Wsm[(n * 8 + (c8 ^ (n & 7))) * 8]) = v;
        }
        {
            unsigned short o[8];
            if (f32in) {
                const float* p = Xf + (size_t)(q0 + xrow) * HCH + kk + xc8 * 8;
                float4 a = *reinterpret_cast<const float4*>(p);
                float4 b = *reinterpret_cast<const float4*>(p + 4);
                o[0]=f2bf(a.x); o[1]=f2bf(a.y); o[2]=f2bf(a.z); o[3]=f2bf(a.w);
                o[4]=f2bf(b.x); o[5]=f2bf(b.y); o[6]=f2bf(b.z); o[7]=f2bf(b.w);
            } else {
                *reinterpret_cast<uint4*>(o) =
                    *reinterpret_cast<const uint4*>(Xb + (size_t)(q0 + xrow) * HCH + kk + xc8 * 8);
            }
            *reinterpret_cast<uint4*>(&Xsm[(xrow * 8 + (xc8 ^ (xrow & 7))) * 8]) =
                *reinterpret_cast<uint4*>(o);
        }
        __syncthreads();
#pragma unroll
        for (int ks = 0; ks < 2; ks++) {
            short8 af = *reinterpret_cast<const short8*>(
                &Xsm[(arow * 8 + ((ks * 4 + g) ^ (c & 7))) * 8]);
#pragma unroll
            for (int nt = 0; nt < 4; nt++) {
                int n = (w >> 1) * 64 + nt * 16 + c;
                short8 bf = *reinterpret_cast<const short8*>(
                    &Wsm[(n * 8 + ((ks * 4 + g) ^ (c & 7))) * 8]);
                acc[nt] = __builtin_amdgcn_mfma_f32_16x16x32_bf16(af, bf, acc[nt], 0, 0, 0);
            }
        }
    }
    unsigned short* dst = (blockIdx.y == 0) ? Qb : (blockIdx.y == 1) ? Kb : Vb;
#pragma unroll
    for (int nt = 0; nt < 4; nt++) {
        int n = (w >> 1) * 64 + nt * 16 + c;
#pragma unroll
        for (int r = 0; r < 4; r++) {
            int rr = q0 + (w & 1) * 16 + g * 4 + r;
            dst[(size_t)rr * DDIM + n] = f2bf(acc[nt][r]);
        }
    }
}

// ---------------------------------------------------------------------------
// Kernel 2: V [8192][128] -> VT [128][8192]  (unchanged)
// ---------------------------------------------------------------------------
__global__ __launch_bounds__(256) void vtrans(
    const unsigned short* __restrict__ V, unsigned short* __restrict__ VT)
{
    __shared__ unsigned short T[32 * 33];
    const int t = threadIdx.x;
    const int k0 = blockIdx.x * 32, d0 = blockIdx.y * 32;
    {
        int key = t >> 3, dq = (t & 7) * 4;
        ushort4 v = *reinterpret_cast<const ushort4*>(V + (size_t)(k0 + key) * DDIM + d0 + dq);
        T[(dq + 0) * 33 + key] = v.x;
        T[(dq + 1) * 33 + key] = v.y;
        T[(dq + 2) * 33 + key] = v.z;
        T[(dq + 3) * 33 + key] = v.w;
    }
    __syncthreads();
    {
        int d = t >> 3, kq = (t & 7) * 4;
        ushort4 o;
        o.x = T[d * 33 + kq + 0]; o.y = T[d * 33 + kq + 1];
        o.z = T[d * 33 + kq + 2]; o.w = T[d * 33 + kq + 3];
        *reinterpret_cast<ushort4*>(VT + (size_t)(d0 + d) * NTOK + k0 + kq) = o;
    }
}

// ---------------------------------------------------------------------------
// Kernel 3: flash partials v3 (unchanged from r7). Packed-bit mask.
// ---------------------------------------------------------------------------
__global__ __launch_bounds__(256, 4) void attn_part(
    const unsigned short* __restrict__ Qb, const unsigned short* __restrict__ Kb,
    const unsigned short* __restrict__ VT, const unsigned long long* __restrict__ Mp,
    _Float16* __restrict__ Opart, float* __restrict__ lpart, int kps)
{
    __shared__ unsigned short Ksm[64 * 128];
    __shared__ unsigned short Vsm[128 * 64];
    __shared__ unsigned short Psm[4 * 16 * 64];
    const int tid  = threadIdx.x;
    const int lane = tid & 63, w = tid >> 6;
    const int c = lane & 15, g = lane >> 4;
    const int q0 = blockIdx.x * 64;
    const int split = blockIdx.y;
    const int kbase = split * kps;
    const int niter = kps >> 6;
    const int tb0 = kbase >> 6;
    unsigned short* Pw = &Psm[w * 16 * 64];

    short8 qf[4];
#pragma unroll
    for (int ks = 0; ks < 4; ks++)
        qf[ks] = *reinterpret_cast<const short8*>(Qb + (size_t)(q0 + w * 16 + c) * DDIM + ks * 32 + g * 8);

    short8 ones;
#pragma unroll
    for (int i = 0; i < 8; i++) ones[i] = (short)0x3F80;   // bf16 1.0

    f32x4 accO[8];
#pragma unroll
    for (int i = 0; i < 8; i++) accO[i] = (f32x4){0.f, 0.f, 0.f, 0.f};
    f32x4 accL = (f32x4){0.f, 0.f, 0.f, 0.f};

    unsigned long long mp[4], mpn[4];
#pragma unroll
    for (int r = 0; r < 4; r++)
        mp[r] = Mp[(size_t)(q0 + w * 16 + g * 4 + r) * 128 + tb0];

    for (int t = 0; t < niter; t++) {
        const int k0 = kbase + t * 64;
        __syncthreads();
#pragma unroll
        for (int i = 0; i < 4; i++) {                 // stage K tile [64][128]
            int cid = tid + 256 * i;
            int rowk = cid >> 4, c16 = cid & 15;
            uint4 v = *reinterpret_cast<const uint4*>(Kb + (size_t)(k0 + rowk) * DDIM + c16 * 8);
            *reinterpret_cast<uint4*>(&Ksm[(rowk * 16 + (c16 ^ (rowk & 15))) * 8]) = v;
        }
#pragma unroll
        for (int i = 0; i < 4; i++) {                 // stage VT tile [128][64]
            int cid = tid + 256 * i;
            int d = cid >> 3, c8 = cid & 7;
            uint4 v = *reinterpret_cast<const uint4*>(VT + (size_t)d * NTOK + k0 + c8 * 8);
            *reinterpret_cast<uint4*>(&Vsm[(d * 8 + (c8 ^ (d & 7))) * 8]) = v;
        }
        if (t + 1 < niter) {
#pragma unroll
            for (int r = 0; r < 4; r++)
                mpn[r] = Mp[(size_t)(q0 + w * 16 + g * 4 + r) * 128 + tb0 + t + 1];
        }
        __syncthreads();

        f32x4 sacc[4];
#pragma unroll
        for (int nt = 0; nt < 4; nt++) {
            sacc[nt] = (f32x4){0.f, 0.f, 0.f, 0.f};
#pragma unroll
            for (int ks = 0; ks < 4; ks++) {
                short8 bf = *reinterpret_cast<const short8*>(
                    &Ksm[((nt * 16 + c) * 16 + ((ks * 4 + g) ^ c)) * 8]);
                sacc[nt] = __builtin_amdgcn_mfma_f32_16x16x32_bf16(qf[ks], bf, sacc[nt], 0, 0, 0);
            }
        }

#pragma unroll
        for (int nt = 0; nt < 4; nt++)
#pragma unroll
            for (int r = 0; r < 4; r++) {
                bool mv = (mp[r] >> (nt * 16 + c)) & 1ull;
                float p = mv ? 0.f : __expf(sacc[nt][r] * (1.0f / 128.0f));
                int row = g * 4 + r;
                Pw[(row * 8 + ((nt * 2 + (c >> 3)) ^ (row & 7))) * 8 + (c & 7)] = f2bf(p);
            }
#pragma unroll
        for (int r = 0; r < 4; r++) mp[r] = mpn[r];

#pragma unroll
        for (int ks2 = 0; ks2 < 2; ks2++) {
            short8 af = *reinterpret_cast<const short8*>(
                &Pw[(c * 8 + ((ks2 * 4 + g) ^ (c & 7))) * 8]);
            accL = __builtin_amdgcn_mfma_f32_16x16x32_bf16(af, ones, accL, 0, 0, 0);
#pragma unroll
            for (int dt = 0; dt < 8; dt++) {
                short8 bfv = *reinterpret_cast<const short8*>(
                    &Vsm[((dt * 16 + c) * 8 + ((ks2 * 4 + g) ^ (c & 7))) * 8]);
                accO[dt] = __builtin_amdgcn_mfma_f32_16x16x32_bf16(af, bfv, accO[dt], 0, 0, 0);
            }
        }
    }

    _Float16* Op = Opart + (size_t)split * NTOK * DDIM;
#pragma unroll
    for (int nt = 0; nt < 8; nt++)
#pragma unroll
        for (int r = 0; r < 4; r++)
            Op[(size_t)(q0 + w * 16 + g * 4 + r) * DDIM + nt * 16 + c] = (_Float16)accO[nt][r];
    if (c == 0) {
#pragma unroll
        for (int r = 0; r < 4; r++)
            lpart[(size_t)split * NTOK + q0 + w * 16 + g * 4 + r] = accL[r];
    }
}

// ---------------------------------------------------------------------------
// Kernel 4: combine nsplit key-splits -> fp32 out.
// ---------------------------------------------------------------------------
__global__ __launch_bounds__(256) void combine(
    const _Float16* __restrict__ Opart, const float* __restrict__ lpart,
    float* __restrict__ out, int nsplit)
{
    int idx = blockIdx.x * 256 + threadIdx.x;
    int row = idx >> 7;
    const size_t S = (size_t)NTOK * DDIM;
    float den = 0.f, num = 0.f;
    for (int s = 0; s < nsplit; s++) {
        den += lpart[(size_t)s * NTOK + row];
        num += (float)Opart[(size_t)s * S + idx];
    }
    out[idx] = (den > 0.f) ? (num / den) : 0.f;
}

// ---------------------------------------------------------------------------
extern "C" void kernel_launch(void* const* d_in, const int* in_sizes, int n_in,
                              void* d_out, int out_size, void* d_ws, size_t ws_size,
                              hipStream_t stream)
{
    const void* X = d_in[0]; const void* mask = d_in[1]; const void* W = d_in[2];
    {
        const void* x_ = nullptr; const void* m_ = nullptr; const void* w_ = nullptr;
        for (int i = 0; i < n_in; i++) {
            if (in_sizes[i] == 16777216) x_ = d_in[i];
            else if (in_sizes[i] == 67108864) m_ = d_in[i];
            else if (in_sizes[i] == 786432) w_ = d_in[i];
        }
        if (x_ && m_ && w_) { X = x_; mask = m_; W = w_; }
    }
    float* out = (float*)d_out;                 // fp32 [8192][128]

    const int nsplit = (ws_size >= (33ull << 20)) ? 8 : 4;
    const int kps = NTOK / nsplit;

    char* ws = (char*)d_ws;
    unsigned short* Qb  = (unsigned short*)(ws);                    // 0..2 MB
    unsigned short* Kb  = (unsigned short*)(ws + (2ull << 20));     // 2..4
    unsigned short* VT  = (unsigned short*)(ws + (4ull << 20));     // 4..6
    unsigned long long* Mpk = (unsigned long long*)(ws + (6ull << 20)); // 6..14
    _Float16*       Opart = (_Float16*)(ws + (14ull << 20));        // 14..14+2*nsplit
    unsigned short* Wbf = (unsigned short*)(ws + (14ull << 20));    // aliases Opart (dead before attn)
    unsigned short* Vb  = (unsigned short*)(ws + (14ull << 20) + (1536ull << 10)); // dead after vtrans
    float*          lpart = (float*)(ws + (14ull << 20) + ((size_t)nsplit << 21)); // after Opart
    int*            flags = (int*)((char*)lpart + (128ull << 10));

    detect_kernel<<<1, 64, 0, stream>>>((const unsigned int*)X, (const unsigned int*)mask, flags);
    conv_w<<<dim3(384), 256, 0, stream>>>(W, flags, Wbf);
    mask_pack<<<dim3(2048), 256, 0, stream>>>(mask, flags, (unsigned char*)Mpk);
    qkv_gemm<<<dim3(256, 3), 256, 0, stream>>>(X, Wbf, flags, Qb, Kb, Vb);
    vtrans<<<dim3(256, 4), 256, 0, stream>>>(Vb, VT);
    attn_part<<<dim3(128, nsplit), 256, 0, stream>>>(Qb, Kb, VT, Mpk, Opart, lpart, kps);
    combine<<<dim3(4096), 256, 0, stream>>>(Opart, lpart, out, nsplit);
}

// Round 9
// 616.527 us; speedup vs baseline: 1.3978x; 1.0050x over previous
//
#include <hip/hip_runtime.h>
#include <hip/hip_bf16.h>

typedef __attribute__((ext_vector_type(8))) short short8;
typedef __attribute__((ext_vector_type(4))) float f32x4;

#define NTOK 8192
#define HCH  2048
#define DDIM 128

__device__ __forceinline__ unsigned short f2bf(float f) {
    __hip_bfloat16 h = __float2bfloat16(f);   // RNE
    return *reinterpret_cast<unsigned short*>(&h);
}

// ---------------------------------------------------------------------------
// Kernel 0: runtime dtype detection v2 (one wave, parallel).
// flags[0]: 1 -> X/W fp32, 0 -> bf16.
// flags[1]: mask mode: 0=u32 word, 1=byte, 2=u16, 3=packed bits.
// ---------------------------------------------------------------------------
__global__ void detect_kernel(const unsigned int* __restrict__ X,
                              const unsigned int* __restrict__ M,
                              int* __restrict__ flags)
{
    const int lane = threadIdx.x & 63;
    unsigned int e = (X[lane] >> 7) & 0xFF;
    unsigned long long hb = __ballot(e >= 110 && e <= 140);

    bool w_ok = true, h_ok = true, b_ok = true;
#pragma unroll
    for (int i = 0; i < 16; i++) {
        unsigned int u = M[lane + 64 * i];
        if (!(u == 0u || u == 1u || u == 0x3F800000u)) w_ok = false;
        unsigned int h0 = u & 0xFFFFu, h1 = u >> 16;
        bool o0 = (h0 == 0u || h0 == 0x3F80u || h0 == 0x3C00u || h0 == 1u);
        bool o1 = (h1 == 0u || h1 == 0x3F80u || h1 == 0x3C00u || h1 == 1u);
        if (!(o0 && o1)) h_ok = false;
        unsigned int b0 = u & 0xFF, b1 = (u >> 8) & 0xFF,
                     b2 = (u >> 16) & 0xFF, b3 = u >> 24;
        if (b0 > 1u || b1 > 1u || b2 > 1u || b3 > 1u) b_ok = false;
    }
    bool allw = __all(w_ok), allh = __all(h_ok), allb = __all(b_ok);
    if (lane == 0) {
        flags[0] = (__popcll(hb) < 32) ? 1 : 0;
        flags[1] = allw ? 0 : (allb ? 1 : (allh ? 2 : 3));
    }
}

// ---------------------------------------------------------------------------
// Kernel 0b: W -> bf16 (copy if already bf16).
// ---------------------------------------------------------------------------
__global__ __launch_bounds__(256) void conv_w(
    const void* __restrict__ Wv, const int* __restrict__ flags,
    unsigned short* __restrict__ Wbf)
{
    int t = blockIdx.x * 256 + threadIdx.x;
    size_t off = (size_t)t * 8;
    if (flags[0] != 0) {
        const float* Wf = (const float*)Wv;
        float4 a = *reinterpret_cast<const float4*>(Wf + off);
        float4 b = *reinterpret_cast<const float4*>(Wf + off + 4);
        unsigned short o[8] = { f2bf(a.x), f2bf(a.y), f2bf(a.z), f2bf(a.w),
                                f2bf(b.x), f2bf(b.y), f2bf(b.z), f2bf(b.w) };
        *reinterpret_cast<uint4*>(Wbf + off) = *reinterpret_cast<uint4*>(o);
    } else {
        *reinterpret_cast<uint4*>(Wbf + off) =
            *reinterpret_cast<const uint4*>((const unsigned short*)Wv + off);
    }
}

// ---------------------------------------------------------------------------
// Kernel 0c: mask -> 1 bit/elem (thread per output byte, coalesced).
// ---------------------------------------------------------------------------
__global__ __launch_bounds__(256) void mask_pack(
    const void* __restrict__ maskv, const int* __restrict__ flags,
    unsigned char* __restrict__ Mp)
{
    const int mmode = flags[1];
    const int NB = NTOK * (NTOK / 8);          // 8 Mi bytes
    int t0 = blockIdx.x * 256 + threadIdx.x;
    for (int b = t0; b < NB; b += 2048 * 256) {
        unsigned int byte = 0;
        if (mmode == 0) {
            const uint4* p = reinterpret_cast<const uint4*>(
                (const unsigned int*)maskv + (size_t)b * 8);
            uint4 a = p[0], c = p[1];
            byte = (a.x != 0u) | ((a.y != 0u) << 1) | ((a.z != 0u) << 2) | ((a.w != 0u) << 3)
                 | ((c.x != 0u) << 4) | ((c.y != 0u) << 5) | ((c.z != 0u) << 6) | ((c.w != 0u) << 7);
        } else if (mmode == 1) {
            unsigned long long v = *reinterpret_cast<const unsigned long long*>(
                (const unsigned char*)maskv + (size_t)b * 8);
#pragma unroll
            for (int k = 0; k < 8; k++)
                byte |= (((v >> (8 * k)) & 0xFFull) != 0ull) << k;
        } else if (mmode == 2) {
            uint4 a = *reinterpret_cast<const uint4*>(
                (const unsigned short*)maskv + (size_t)b * 8);
            byte = ((a.x & 0xFFFFu) != 0u) | ((a.x >> 16 != 0u) << 1)
                 | (((a.y & 0xFFFFu) != 0u) << 2) | ((a.y >> 16 != 0u) << 3)
                 | (((a.z & 0xFFFFu) != 0u) << 4) | ((a.z >> 16 != 0u) << 5)
                 | (((a.w & 0xFFFFu) != 0u) << 6) | ((a.w >> 16 != 0u) << 7);
        } else {
            byte = ((const unsigned char*)maskv)[b];
        }
        Mp[b] = (unsigned char)byte;
    }
}

// ---------------------------------------------------------------------------
// Kernel 1: QKV projection (unchanged).
// ---------------------------------------------------------------------------
__global__ __launch_bounds__(256) void qkv_gemm(
    const void* __restrict__ Xv, const unsigned short* __restrict__ Wbf,
    const int* __restrict__ flags,
    unsigned short* __restrict__ Qb, unsigned short* __restrict__ Kb,
    unsigned short* __restrict__ Vb)
{
    __shared__ unsigned short Wsm[128 * 64];
    __shared__ unsigned short Xsm[32 * 64];
    const int tid  = threadIdx.x;
    const int lane = tid & 63, w = tid >> 6;
    const int c = lane & 15, g = lane >> 4;
    const int q0 = blockIdx.x * 32;
    const int n0 = blockIdx.y * 128;
    const bool f32in = (flags[0] != 0);
    const float*          Xf = (const float*)Xv;
    const unsigned short* Xb = (const unsigned short*)Xv;

    f32x4 acc[4];
#pragma unroll
    for (int i = 0; i < 4; i++) acc[i] = (f32x4){0.f, 0.f, 0.f, 0.f};

    const int xrow = tid >> 3, xc8 = tid & 7;
    const int arow = (w & 1) * 16 + c;

    for (int kk = 0; kk < HCH; kk += 64) {
        __syncthreads();
#pragma unroll
        for (int i = 0; i < 4; i++) {
            int cid = tid + 256 * i;
            int n = cid >> 3, c8 = cid & 7;
            uint4 v = *reinterpret_cast<const uint4*>(Wbf + (size_t)(n0 + n) * HCH + kk + c8 * 8);
            *reinterpret_cast<uint4*>(&Wsm[(n * 8 + (c8 ^ (n & 7))) * 8]) = v;
        }
        {
            unsigned short o[8];
            if (f32in) {
                const float* p = Xf + (size_t)(q0 + xrow) * HCH + kk + xc8 * 8;
                float4 a = *reinterpret_cast<const float4*>(p);
                float4 b = *reinterpret_cast<const float4*>(p + 4);
                o[0]=f2bf(a.x); o[1]=f2bf(a.y); o[2]=f2bf(a.z); o[3]=f2bf(a.w);
                o[4]=f2bf(b.x); o[5]=f2bf(b.y); o[6]=f2bf(b.z); o[7]=f2bf(b.w);
            } else {
                *reinterpret_cast<uint4*>(o) =
                    *reinterpret_cast<const uint4*>(Xb + (size_t)(q0 + xrow) * HCH + kk + xc8 * 8);
            }
            *reinterpret_cast<uint4*>(&Xsm[(xrow * 8 + (xc8 ^ (xrow & 7))) * 8]) =
                *reinterpret_cast<uint4*>(o);
        }
        __syncthreads();
#pragma unroll
        for (int ks = 0; ks < 2; ks++) {
            short8 af = *reinterpret_cast<const short8*>(
                &Xsm[(arow * 8 + ((ks * 4 + g) ^ (c & 7))) * 8]);
#pragma unroll
            for (int nt = 0; nt < 4; nt++) {
                int n = (w >> 1) * 64 + nt * 16 + c;
                short8 bf = *reinterpret_cast<const short8*>(
                    &Wsm[(n * 8 + ((ks * 4 + g) ^ (c & 7))) * 8]);
                acc[nt] = __builtin_amdgcn_mfma_f32_16x16x32_bf16(af, bf, acc[nt], 0, 0, 0);
            }
        }
    }
    unsigned short* dst = (blockIdx.y == 0) ? Qb : (blockIdx.y == 1) ? Kb : Vb;
#pragma unroll
    for (int nt = 0; nt < 4; nt++) {
        int n = (w >> 1) * 64 + nt * 16 + c;
#pragma unroll
        for (int r = 0; r < 4; r++) {
            int rr = q0 + (w & 1) * 16 + g * 4 + r;
            dst[(size_t)rr * DDIM + n] = f2bf(acc[nt][r]);
        }
    }
}

// ---------------------------------------------------------------------------
// Kernel 2: V [8192][128] -> VT [128][8192]  (unchanged)
// ---------------------------------------------------------------------------
__global__ __launch_bounds__(256) void vtrans(
    const unsigned short* __restrict__ V, unsigned short* __restrict__ VT)
{
    __shared__ unsigned short T[32 * 33];
    const int t = threadIdx.x;
    const int k0 = blockIdx.x * 32, d0 = blockIdx.y * 32;
    {
        int key = t >> 3, dq = (t & 7) * 4;
        ushort4 v = *reinterpret_cast<const ushort4*>(V + (size_t)(k0 + key) * DDIM + d0 + dq);
        T[(dq + 0) * 33 + key] = v.x;
        T[(dq + 1) * 33 + key] = v.y;
        T[(dq + 2) * 33 + key] = v.z;
        T[(dq + 3) * 33 + key] = v.w;
    }
    __syncthreads();
    {
        int d = t >> 3, kq = (t & 7) * 4;
        ushort4 o;
        o.x = T[d * 33 + kq + 0]; o.y = T[d * 33 + kq + 1];
        o.z = T[d * 33 + kq + 2]; o.w = T[d * 33 + kq + 3];
        *reinterpret_cast<ushort4*>(VT + (size_t)(d0 + d) * NTOK + k0 + kq) = o;
    }
}

// ---------------------------------------------------------------------------
// Kernel 3: flash partials v4. XCD-locality grid: blockIdx.x = split (8),
// blockIdx.y = q-block (128) -> linear id % 8 == split -> all q-blocks of a
// split land on one XCD (round-robin heuristic), making its 512 KB K/VT
// slice L2-resident and killing the 512 MB L2-miss re-fetch stream.
// ---------------------------------------------------------------------------
__global__ __launch_bounds__(256, 4) void attn_part(
    const unsigned short* __restrict__ Qb, const unsigned short* __restrict__ Kb,
    const unsigned short* __restrict__ VT, const unsigned long long* __restrict__ Mp,
    _Float16* __restrict__ Opart, float* __restrict__ lpart, int kps)
{
    __shared__ unsigned short Ksm[64 * 128];
    __shared__ unsigned short Vsm[128 * 64];
    __shared__ unsigned short Psm[4 * 16 * 64];
    const int tid  = threadIdx.x;
    const int lane = tid & 63, w = tid >> 6;
    const int c = lane & 15, g = lane >> 4;
    const int q0 = blockIdx.y * 64;            // q-block (was x)
    const int split = blockIdx.x;              // split   (was y) -> XCD bin
    const int kbase = split * kps;
    const int niter = kps >> 6;
    const int tb0 = kbase >> 6;
    unsigned short* Pw = &Psm[w * 16 * 64];

    short8 qf[4];
#pragma unroll
    for (int ks = 0; ks < 4; ks++)
        qf[ks] = *reinterpret_cast<const short8*>(Qb + (size_t)(q0 + w * 16 + c) * DDIM + ks * 32 + g * 8);

    short8 ones;
#pragma unroll
    for (int i = 0; i < 8; i++) ones[i] = (short)0x3F80;   // bf16 1.0

    f32x4 accO[8];
#pragma unroll
    for (int i = 0; i < 8; i++) accO[i] = (f32x4){0.f, 0.f, 0.f, 0.f};
    f32x4 accL = (f32x4){0.f, 0.f, 0.f, 0.f};

    unsigned long long mp[4], mpn[4];
#pragma unroll
    for (int r = 0; r < 4; r++)
        mp[r] = Mp[(size_t)(q0 + w * 16 + g * 4 + r) * 128 + tb0];

    for (int t = 0; t < niter; t++) {
        const int k0 = kbase + t * 64;
        __syncthreads();
#pragma unroll
        for (int i = 0; i < 4; i++) {                 // stage K tile [64][128]
            int cid = tid + 256 * i;
            int rowk = cid >> 4, c16 = cid & 15;
            uint4 v = *reinterpret_cast<const uint4*>(Kb + (size_t)(k0 + rowk) * DDIM + c16 * 8);
            *reinterpret_cast<uint4*>(&Ksm[(rowk * 16 + (c16 ^ (rowk & 15))) * 8]) = v;
        }
#pragma unroll
        for (int i = 0; i < 4; i++) {                 // stage VT tile [128][64]
            int cid = tid + 256 * i;
            int d = cid >> 3, c8 = cid & 7;
            uint4 v = *reinterpret_cast<const uint4*>(VT + (size_t)d * NTOK + k0 + c8 * 8);
            *reinterpret_cast<uint4*>(&Vsm[(d * 8 + (c8 ^ (d & 7))) * 8]) = v;
        }
        if (t + 1 < niter) {
#pragma unroll
            for (int r = 0; r < 4; r++)
                mpn[r] = Mp[(size_t)(q0 + w * 16 + g * 4 + r) * 128 + tb0 + t + 1];
        }
        __syncthreads();

        f32x4 sacc[4];
#pragma unroll
        for (int nt = 0; nt < 4; nt++) {
            sacc[nt] = (f32x4){0.f, 0.f, 0.f, 0.f};
#pragma unroll
            for (int ks = 0; ks < 4; ks++) {
                short8 bf = *reinterpret_cast<const short8*>(
                    &Ksm[((nt * 16 + c) * 16 + ((ks * 4 + g) ^ c)) * 8]);
                sacc[nt] = __builtin_amdgcn_mfma_f32_16x16x32_bf16(qf[ks], bf, sacc[nt], 0, 0, 0);
            }
        }

#pragma unroll
        for (int nt = 0; nt < 4; nt++)
#pragma unroll
            for (int r = 0; r < 4; r++) {
                bool mv = (mp[r] >> (nt * 16 + c)) & 1ull;
                float p = mv ? 0.f : __expf(sacc[nt][r] * (1.0f / 128.0f));
                int row = g * 4 + r;
                Pw[(row * 8 + ((nt * 2 + (c >> 3)) ^ (row & 7))) * 8 + (c & 7)] = f2bf(p);
            }
#pragma unroll
        for (int r = 0; r < 4; r++) mp[r] = mpn[r];

#pragma unroll
        for (int ks2 = 0; ks2 < 2; ks2++) {
            short8 af = *reinterpret_cast<const short8*>(
                &Pw[(c * 8 + ((ks2 * 4 + g) ^ (c & 7))) * 8]);
            accL = __builtin_amdgcn_mfma_f32_16x16x32_bf16(af, ones, accL, 0, 0, 0);
#pragma unroll
            for (int dt = 0; dt < 8; dt++) {
                short8 bfv = *reinterpret_cast<const short8*>(
                    &Vsm[((dt * 16 + c) * 8 + ((ks2 * 4 + g) ^ (c & 7))) * 8]);
                accO[dt] = __builtin_amdgcn_mfma_f32_16x16x32_bf16(af, bfv, accO[dt], 0, 0, 0);
            }
        }
    }

    _Float16* Op = Opart + (size_t)split * NTOK * DDIM;
#pragma unroll
    for (int nt = 0; nt < 8; nt++)
#pragma unroll
        for (int r = 0; r < 4; r++)
            Op[(size_t)(q0 + w * 16 + g * 4 + r) * DDIM + nt * 16 + c] = (_Float16)accO[nt][r];
    if (c == 0) {
#pragma unroll
        for (int r = 0; r < 4; r++)
            lpart[(size_t)split * NTOK + q0 + w * 16 + g * 4 + r] = accL[r];
    }
}

// ---------------------------------------------------------------------------
// Kernel 4: combine nsplit key-splits -> fp32 out.
// ---------------------------------------------------------------------------
__global__ __launch_bounds__(256) void combine(
    const _Float16* __restrict__ Opart, const float* __restrict__ lpart,
    float* __restrict__ out, int nsplit)
{
    int idx = blockIdx.x * 256 + threadIdx.x;
    int row = idx >> 7;
    const size_t S = (size_t)NTOK * DDIM;
    float den = 0.f, num = 0.f;
    for (int s = 0; s < nsplit; s++) {
        den += lpart[(size_t)s * NTOK + row];
        num += (float)Opart[(size_t)s * S + idx];
    }
    out[idx] = (den > 0.f) ? (num / den) : 0.f;
}

// ---------------------------------------------------------------------------
extern "C" void kernel_launch(void* const* d_in, const int* in_sizes, int n_in,
                              void* d_out, int out_size, void* d_ws, size_t ws_size,
                              hipStream_t stream)
{
    const void* X = d_in[0]; const void* mask = d_in[1]; const void* W = d_in[2];
    {
        const void* x_ = nullptr; const void* m_ = nullptr; const void* w_ = nullptr;
        for (int i = 0; i < n_in; i++) {
            if (in_sizes[i] == 16777216) x_ = d_in[i];
            else if (in_sizes[i] == 67108864) m_ = d_in[i];
            else if (in_sizes[i] == 786432) w_ = d_in[i];
        }
        if (x_ && m_ && w_) { X = x_; mask = m_; W = w_; }
    }
    float* out = (float*)d_out;                 // fp32 [8192][128]

    const int nsplit = (ws_size >= (33ull << 20)) ? 8 : 4;
    const int kps = NTOK / nsplit;

    char* ws = (char*)d_ws;
    unsigned short* Qb  = (unsigned short*)(ws);                    // 0..2 MB
    unsigned short* Kb  = (unsigned short*)(ws + (2ull << 20));     // 2..4
    unsigned short* VT  = (unsigned short*)(ws + (4ull << 20));     // 4..6
    unsigned long long* Mpk = (unsigned long long*)(ws + (6ull << 20)); // 6..14
    _Float16*       Opart = (_Float16*)(ws + (14ull << 20));        // 14..14+2*nsplit
    unsigned short* Wbf = (unsigned short*)(ws + (14ull << 20));    // aliases Opart (dead before attn)
    unsigned short* Vb  = (unsigned short*)(ws + (14ull << 20) + (1536ull << 10)); // dead after vtrans
    float*          lpart = (float*)(ws + (14ull << 20) + ((size_t)nsplit << 21)); // after Opart
    int*            flags = (int*)((char*)lpart + (128ull << 10));

    detect_kernel<<<1, 64, 0, stream>>>((const unsigned int*)X, (const unsigned int*)mask, flags);
    conv_w<<<dim3(384), 256, 0, stream>>>(W, flags, Wbf);
    mask_pack<<<dim3(2048), 256, 0, stream>>>(mask, flags, (unsigned char*)Mpk);
    qkv_gemm<<<dim3(256, 3), 256, 0, stream>>>(X, Wbf, flags, Qb, Kb, Vb);
    vtrans<<<dim3(256, 4), 256, 0, stream>>>(Vb, VT);
    attn_part<<<dim3(nsplit, 128), 256, 0, stream>>>(Qb, Kb, VT, Mpk, Opart, lpart, kps);
    combine<<<dim3(4096), 256, 0, stream>>>(Opart, lpart, out, nsplit);
}

// Round 10
// 544.664 us; speedup vs baseline: 1.5822x; 1.1319x over previous
//
#include <hip/hip_runtime.h>
#include <hip/hip_bf16.h>

typedef __attribute__((ext_vector_type(8))) short short8;
typedef __attribute__((ext_vector_type(4))) float f32x4;

#define NTOK 8192
#define HCH  2048
#define DDIM 128
#define NSPLIT 8
#define KPS   (NTOK / NSPLIT)     // 1024
#define NITER (KPS / 64)          // 16

__device__ __forceinline__ unsigned short f2bf(float f) {
    __hip_bfloat16 h = __float2bfloat16(f);
    return *reinterpret_cast<unsigned short*>(&h);
}
__device__ __forceinline__ unsigned short f2h(float f) {
    _Float16 h = (_Float16)f;
    return *reinterpret_cast<unsigned short*>(&h);
}

// ---------------------------------------------------------------------------
// Kernel 0: runtime dtype detection (one wave, parallel).
// ---------------------------------------------------------------------------
__global__ void detect_kernel(const unsigned int* __restrict__ X,
                              const unsigned int* __restrict__ M,
                              int* __restrict__ flags)
{
    const int lane = threadIdx.x & 63;
    unsigned int e = (X[lane] >> 7) & 0xFF;
    unsigned long long hb = __ballot(e >= 110 && e <= 140);

    bool w_ok = true, h_ok = true, b_ok = true;
#pragma unroll
    for (int i = 0; i < 16; i++) {
        unsigned int u = M[lane + 64 * i];
        if (!(u == 0u || u == 1u || u == 0x3F800000u)) w_ok = false;
        unsigned int h0 = u & 0xFFFFu, h1 = u >> 16;
        bool o0 = (h0 == 0u || h0 == 0x3F80u || h0 == 0x3C00u || h0 == 1u);
        bool o1 = (h1 == 0u || h1 == 0x3F80u || h1 == 0x3C00u || h1 == 1u);
        if (!(o0 && o1)) h_ok = false;
        unsigned int b0 = u & 0xFF, b1 = (u >> 8) & 0xFF,
                     b2 = (u >> 16) & 0xFF, b3 = u >> 24;
        if (b0 > 1u || b1 > 1u || b2 > 1u || b3 > 1u) b_ok = false;
    }
    bool allw = __all(w_ok), allh = __all(h_ok), allb = __all(b_ok);
    if (lane == 0) {
        flags[0] = (__popcll(hb) < 32) ? 1 : 0;
        flags[1] = allw ? 0 : (allb ? 1 : (allh ? 2 : 3));
    }
}

// ---------------------------------------------------------------------------
// Kernel 0b: W -> bf16.
// ---------------------------------------------------------------------------
__global__ __launch_bounds__(256) void conv_w(
    const void* __restrict__ Wv, const int* __restrict__ flags,
    unsigned short* __restrict__ Wbf)
{
    int t = blockIdx.x * 256 + threadIdx.x;
    size_t off = (size_t)t * 8;
    if (flags[0] != 0) {
        const float* Wf = (const float*)Wv;
        float4 a = *reinterpret_cast<const float4*>(Wf + off);
        float4 b = *reinterpret_cast<const float4*>(Wf + off + 4);
        unsigned short o[8] = { f2bf(a.x), f2bf(a.y), f2bf(a.z), f2bf(a.w),
                                f2bf(b.x), f2bf(b.y), f2bf(b.z), f2bf(b.w) };
        *reinterpret_cast<uint4*>(Wbf + off) = *reinterpret_cast<uint4*>(o);
    } else {
        *reinterpret_cast<uint4*>(Wbf + off) =
            *reinterpret_cast<const uint4*>((const unsigned short*)Wv + off);
    }
}

// ---------------------------------------------------------------------------
// Kernel 0c: mask -> 1 bit/elem (thread per output byte, coalesced).
// ---------------------------------------------------------------------------
__global__ __launch_bounds__(256) void mask_pack(
    const void* __restrict__ maskv, const int* __restrict__ flags,
    unsigned char* __restrict__ Mp)
{
    const int mmode = flags[1];
    const int NB = NTOK * (NTOK / 8);
    int t0 = blockIdx.x * 256 + threadIdx.x;
    for (int b = t0; b < NB; b += 2048 * 256) {
        unsigned int byte = 0;
        if (mmode == 0) {
            const uint4* p = reinterpret_cast<const uint4*>(
                (const unsigned int*)maskv + (size_t)b * 8);
            uint4 a = p[0], c = p[1];
            byte = (a.x != 0u) | ((a.y != 0u) << 1) | ((a.z != 0u) << 2) | ((a.w != 0u) << 3)
                 | ((c.x != 0u) << 4) | ((c.y != 0u) << 5) | ((c.z != 0u) << 6) | ((c.w != 0u) << 7);
        } else if (mmode == 1) {
            unsigned long long v = *reinterpret_cast<const unsigned long long*>(
                (const unsigned char*)maskv + (size_t)b * 8);
#pragma unroll
            for (int k = 0; k < 8; k++)
                byte |= (((v >> (8 * k)) & 0xFFull) != 0ull) << k;
        } else if (mmode == 2) {
            uint4 a = *reinterpret_cast<const uint4*>(
                (const unsigned short*)maskv + (size_t)b * 8);
            byte = ((a.x & 0xFFFFu) != 0u) | ((a.x >> 16 != 0u) << 1)
                 | (((a.y & 0xFFFFu) != 0u) << 2) | ((a.y >> 16 != 0u) << 3)
                 | (((a.z & 0xFFFFu) != 0u) << 4) | ((a.z >> 16 != 0u) << 5)
                 | (((a.w & 0xFFFFu) != 0u) << 6) | ((a.w >> 16 != 0u) << 7);
        } else {
            byte = ((const unsigned char*)maskv)[b];
        }
        Mp[b] = (unsigned char)byte;
    }
}

// ---------------------------------------------------------------------------
// Kernel 1: QKV projection (unchanged).
// ---------------------------------------------------------------------------
__global__ __launch_bounds__(256) void qkv_gemm(
    const void* __restrict__ Xv, const unsigned short* __restrict__ Wbf,
    const int* __restrict__ flags,
    unsigned short* __restrict__ Qb, unsigned short* __restrict__ Kb,
    unsigned short* __restrict__ Vb)
{
    __shared__ unsigned short Wsm[128 * 64];
    __shared__ unsigned short Xsm[32 * 64];
    const int tid  = threadIdx.x;
    const int lane = tid & 63, w = tid >> 6;
    const int c = lane & 15, g = lane >> 4;
    const int q0 = blockIdx.x * 32;
    const int n0 = blockIdx.y * 128;
    const bool f32in = (flags[0] != 0);
    const float*          Xf = (const float*)Xv;
    const unsigned short* Xb = (const unsigned short*)Xv;

    f32x4 acc[4];
#pragma unroll
    for (int i = 0; i < 4; i++) acc[i] = (f32x4){0.f, 0.f, 0.f, 0.f};

    const int xrow = tid >> 3, xc8 = tid & 7;
    const int arow = (w & 1) * 16 + c;

    for (int kk = 0; kk < HCH; kk += 64) {
        __syncthreads();
#pragma unroll
        for (int i = 0; i < 4; i++) {
            int cid = tid + 256 * i;
            int n = cid >> 3, c8 = cid & 7;
            uint4 v = *reinterpret_cast<const uint4*>(Wbf + (size_t)(n0 + n) * HCH + kk + c8 * 8);
            *reinterpret_cast<uint4*>(&Wsm[(n * 8 + (c8 ^ (n & 7))) * 8]) = v;
        }
        {
            unsigned short o[8];
            if (f32in) {
                const float* p = Xf + (size_t)(q0 + xrow) * HCH + kk + xc8 * 8;
                float4 a = *reinterpret_cast<const float4*>(p);
                float4 b = *reinterpret_cast<const float4*>(p + 4);
                o[0]=f2bf(a.x); o[1]=f2bf(a.y); o[2]=f2bf(a.z); o[3]=f2bf(a.w);
                o[4]=f2bf(b.x); o[5]=f2bf(b.y); o[6]=f2bf(b.z); o[7]=f2bf(b.w);
            } else {
                *reinterpret_cast<uint4*>(o) =
                    *reinterpret_cast<const uint4*>(Xb + (size_t)(q0 + xrow) * HCH + kk + xc8 * 8);
            }
            *reinterpret_cast<uint4*>(&Xsm[(xrow * 8 + (xc8 ^ (xrow & 7))) * 8]) =
                *reinterpret_cast<uint4*>(o);
        }
        __syncthreads();
#pragma unroll
        for (int ks = 0; ks < 2; ks++) {
            short8 af = *reinterpret_cast<const short8*>(
                &Xsm[(arow * 8 + ((ks * 4 + g) ^ (c & 7))) * 8]);
#pragma unroll
            for (int nt = 0; nt < 4; nt++) {
                int n = (w >> 1) * 64 + nt * 16 + c;
                short8 bf = *reinterpret_cast<const short8*>(
                    &Wsm[(n * 8 + ((ks * 4 + g) ^ (c & 7))) * 8]);
                acc[nt] = __builtin_amdgcn_mfma_f32_16x16x32_bf16(af, bf, acc[nt], 0, 0, 0);
            }
        }
    }
    unsigned short* dst = (blockIdx.y == 0) ? Qb : (blockIdx.y == 1) ? Kb : Vb;
#pragma unroll
    for (int nt = 0; nt < 4; nt++) {
        int n = (w >> 1) * 64 + nt * 16 + c;
#pragma unroll
        for (int r = 0; r < 4; r++) {
            int rr = q0 + (w & 1) * 16 + g * 4 + r;
            dst[(size_t)rr * DDIM + n] = f2bf(acc[nt][r]);
        }
    }
}

// ---------------------------------------------------------------------------
// Kernel 2: V -> VT (unchanged).
// ---------------------------------------------------------------------------
__global__ __launch_bounds__(256) void vtrans(
    const unsigned short* __restrict__ V, unsigned short* __restrict__ VT)
{
    __shared__ unsigned short T[32 * 33];
    const int t = threadIdx.x;
    const int k0 = blockIdx.x * 32, d0 = blockIdx.y * 32;
    {
        int key = t >> 3, dq = (t & 7) * 4;
        ushort4 v = *reinterpret_cast<const ushort4*>(V + (size_t)(k0 + key) * DDIM + d0 + dq);
        T[(dq + 0) * 33 + key] = v.x;
        T[(dq + 1) * 33 + key] = v.y;
        T[(dq + 2) * 33 + key] = v.z;
        T[(dq + 3) * 33 + key] = v.w;
    }
    __syncthreads();
    {
        int d = t >> 3, kq = (t & 7) * 4;
        ushort4 o;
        o.x = T[d * 33 + kq + 0]; o.y = T[d * 33 + kq + 1];
        o.z = T[d * 33 + kq + 2]; o.w = T[d * 33 + kq + 3];
        *reinterpret_cast<ushort4*>(VT + (size_t)(d0 + d) * NTOK + k0 + kq) = o;
    }
}

// ---------------------------------------------------------------------------
// Kernel 3: flash partials v5. Tq=128/block (4 waves x 2 row-tiles) halves
// the staged-KV traffic (the measured ~1.9 TB/s L2-miss ceiling binds).
// Opart written in fragment-contiguous layout (16 B/lane stores).
// ---------------------------------------------------------------------------
__global__ __launch_bounds__(256) void attn_part(
    const unsigned short* __restrict__ Qb, const unsigned short* __restrict__ Kb,
    const unsigned short* __restrict__ VT, const unsigned long long* __restrict__ Mp,
    _Float16* __restrict__ Opart, float* __restrict__ lpart)
{
    __shared__ unsigned short Ksm[64 * 128];
    __shared__ unsigned short Vsm[128 * 64];
    __shared__ unsigned short Psm[4 * 16 * 64];
    const int tid  = threadIdx.x;
    const int lane = tid & 63, w = tid >> 6;
    const int c = lane & 15, g = lane >> 4;
    const int split = blockIdx.x;              // 0..7
    const int qb    = blockIdx.y;              // 0..63
    const int q0 = qb * 128;
    const int kbase = split * KPS;
    const int tb0 = kbase >> 6;
    unsigned short* Pw = &Psm[w * 16 * 64];

    // Q fragments for both row-tiles (loop-invariant, 32 VGPRs — fine at 2 blk/CU)
    short8 qf[2][4];
#pragma unroll
    for (int rt = 0; rt < 2; rt++)
#pragma unroll
        for (int ks = 0; ks < 4; ks++)
            qf[rt][ks] = *reinterpret_cast<const short8*>(
                Qb + (size_t)(q0 + w * 32 + rt * 16 + c) * DDIM + ks * 32 + g * 8);

    short8 ones;
#pragma unroll
    for (int i = 0; i < 8; i++) ones[i] = (short)0x3F80;   // bf16 1.0

    f32x4 accO[2][8];
#pragma unroll
    for (int rt = 0; rt < 2; rt++)
#pragma unroll
        for (int i = 0; i < 8; i++) accO[rt][i] = (f32x4){0.f, 0.f, 0.f, 0.f};
    f32x4 accL[2] = {(f32x4){0.f,0.f,0.f,0.f}, (f32x4){0.f,0.f,0.f,0.f}};

    unsigned long long mp[2][4], mpn[2][4];
#pragma unroll
    for (int rt = 0; rt < 2; rt++)
#pragma unroll
        for (int r = 0; r < 4; r++)
            mp[rt][r] = Mp[(size_t)(q0 + w * 32 + rt * 16 + g * 4 + r) * 128 + tb0];

    for (int t = 0; t < NITER; t++) {
        const int k0 = kbase + t * 64;
        __syncthreads();
#pragma unroll
        for (int i = 0; i < 4; i++) {                 // stage K tile [64][128]
            int cid = tid + 256 * i;
            int rowk = cid >> 4, c16 = cid & 15;
            uint4 v = *reinterpret_cast<const uint4*>(Kb + (size_t)(k0 + rowk) * DDIM + c16 * 8);
            *reinterpret_cast<uint4*>(&Ksm[(rowk * 16 + (c16 ^ (rowk & 15))) * 8]) = v;
        }
#pragma unroll
        for (int i = 0; i < 4; i++) {                 // stage VT tile [128][64]
            int cid = tid + 256 * i;
            int d = cid >> 3, c8 = cid & 7;
            uint4 v = *reinterpret_cast<const uint4*>(VT + (size_t)d * NTOK + k0 + c8 * 8);
            *reinterpret_cast<uint4*>(&Vsm[(d * 8 + (c8 ^ (d & 7))) * 8]) = v;
        }
        if (t + 1 < NITER) {
#pragma unroll
            for (int rt = 0; rt < 2; rt++)
#pragma unroll
                for (int r = 0; r < 4; r++)
                    mpn[rt][r] = Mp[(size_t)(q0 + w * 32 + rt * 16 + g * 4 + r) * 128 + tb0 + t + 1];
        }
        __syncthreads();

#pragma unroll
        for (int rt = 0; rt < 2; rt++) {
            f32x4 sacc[4];
#pragma unroll
            for (int nt = 0; nt < 4; nt++) {
                sacc[nt] = (f32x4){0.f, 0.f, 0.f, 0.f};
#pragma unroll
                for (int ks = 0; ks < 4; ks++) {
                    short8 bf = *reinterpret_cast<const short8*>(
                        &Ksm[((nt * 16 + c) * 16 + ((ks * 4 + g) ^ c)) * 8]);
                    sacc[nt] = __builtin_amdgcn_mfma_f32_16x16x32_bf16(qf[rt][ks], bf, sacc[nt], 0, 0, 0);
                }
            }
#pragma unroll
            for (int nt = 0; nt < 4; nt++)
#pragma unroll
                for (int r = 0; r < 4; r++) {
                    bool mv = (mp[rt][r] >> (nt * 16 + c)) & 1ull;
                    float p = mv ? 0.f : __expf(sacc[nt][r] * (1.0f / 128.0f));
                    int row = g * 4 + r;
                    Pw[(row * 8 + ((nt * 2 + (c >> 3)) ^ (row & 7))) * 8 + (c & 7)] = f2bf(p);
                }
            // P written and read by the same wave only (lgkmcnt ordering).
#pragma unroll
            for (int ks2 = 0; ks2 < 2; ks2++) {
                short8 af = *reinterpret_cast<const short8*>(
                    &Pw[(c * 8 + ((ks2 * 4 + g) ^ (c & 7))) * 8]);
                accL[rt] = __builtin_amdgcn_mfma_f32_16x16x32_bf16(af, ones, accL[rt], 0, 0, 0);
#pragma unroll
                for (int dt = 0; dt < 8; dt++) {
                    short8 bfv = *reinterpret_cast<const short8*>(
                        &Vsm[((dt * 16 + c) * 8 + ((ks2 * 4 + g) ^ (c & 7))) * 8]);
                    accO[rt][dt] = __builtin_amdgcn_mfma_f32_16x16x32_bf16(af, bfv, accO[rt][dt], 0, 0, 0);
                }
            }
        }
#pragma unroll
        for (int rt = 0; rt < 2; rt++)
#pragma unroll
            for (int r = 0; r < 4; r++) mp[rt][r] = mpn[rt][r];
    }

    // Fragment-contiguous Opart: per (rt,r) a wave writes 1 KB contiguous.
    // elem offset within wave-chunk(4096): (((rt*4+r)*4+g)*16+c)*8 + dt
    _Float16* Ob = Opart + ((size_t)split * 64 + qb) * (128 * DDIM) + (size_t)w * 4096;
#pragma unroll
    for (int rt = 0; rt < 2; rt++)
#pragma unroll
        for (int r = 0; r < 4; r++) {
            unsigned short o[8];
#pragma unroll
            for (int dt = 0; dt < 8; dt++) o[dt] = f2h(accO[rt][dt][r]);
            *reinterpret_cast<uint4*>(Ob + ((((rt * 4 + r) * 4 + g) * 16 + c) * 8)) =
                *reinterpret_cast<uint4*>(o);
        }
    if (c == 0) {
#pragma unroll
        for (int rt = 0; rt < 2; rt++)
#pragma unroll
            for (int r = 0; r < 4; r++)
                lpart[(size_t)split * NTOK + q0 + w * 32 + rt * 16 + g * 4 + r] = accL[rt][r];
    }
}

// ---------------------------------------------------------------------------
// Kernel 4: combine (inverts the fragment-contiguous Opart layout).
// ---------------------------------------------------------------------------
__global__ __launch_bounds__(256) void combine(
    const _Float16* __restrict__ Opart, const float* __restrict__ lpart,
    float* __restrict__ out)
{
    int idx = blockIdx.x * 256 + threadIdx.x;     // (row, d)
    int row = idx >> 7, d = idx & 127;
    int qb = row >> 7, win = row & 127;
    int w = win >> 5, rt = (win >> 4) & 1, g = (win >> 2) & 3, r = win & 3;
    int nt = d >> 4, c = d & 15;
    size_t off = (size_t)qb * (128 * DDIM) + (size_t)w * 4096
               + ((((rt * 4 + r) * 4 + g) * 16 + c) * 8) + nt;
    const size_t S = (size_t)NTOK * DDIM;
    float den = 0.f, num = 0.f;
#pragma unroll
    for (int s = 0; s < NSPLIT; s++) {
        den += lpart[(size_t)s * NTOK + row];
        num += (float)Opart[(size_t)s * S + off];
    }
    out[idx] = (den > 0.f) ? (num / den) : 0.f;
}

// ---------------------------------------------------------------------------
extern "C" void kernel_launch(void* const* d_in, const int* in_sizes, int n_in,
                              void* d_out, int out_size, void* d_ws, size_t ws_size,
                              hipStream_t stream)
{
    const void* X = d_in[0]; const void* mask = d_in[1]; const void* W = d_in[2];
    {
        const void* x_ = nullptr; const void* m_ = nullptr; const void* w_ = nullptr;
        for (int i = 0; i < n_in; i++) {
            if (in_sizes[i] == 16777216) x_ = d_in[i];
            else if (in_sizes[i] == 67108864) m_ = d_in[i];
            else if (in_sizes[i] == 786432) w_ = d_in[i];
        }
        if (x_ && m_ && w_) { X = x_; mask = m_; W = w_; }
    }
    float* out = (float*)d_out;                 // fp32 [8192][128]

    char* ws = (char*)d_ws;
    unsigned short* Qb  = (unsigned short*)(ws);                    // 0..2 MB
    unsigned short* Kb  = (unsigned short*)(ws + (2ull << 20));     // 2..4
    unsigned short* VT  = (unsigned short*)(ws + (4ull << 20));     // 4..6
    unsigned long long* Mpk = (unsigned long long*)(ws + (6ull << 20)); // 6..14
    _Float16*       Opart = (_Float16*)(ws + (14ull << 20));        // 14..30
    unsigned short* Wbf = (unsigned short*)(ws + (14ull << 20));    // alias (dead before attn)
    unsigned short* Vb  = (unsigned short*)(ws + (14ull << 20) + (1536ull << 10)); // dead after vtrans
    float*          lpart = (float*)(ws + (30ull << 20));           // 30..30.25
    int*            flags = (int*)(ws + (30ull << 20) + (512ull << 10));

    detect_kernel<<<1, 64, 0, stream>>>((const unsigned int*)X, (const unsigned int*)mask, flags);
    conv_w<<<dim3(384), 256, 0, stream>>>(W, flags, Wbf);
    mask_pack<<<dim3(2048), 256, 0, stream>>>(mask, flags, (unsigned char*)Mpk);
    qkv_gemm<<<dim3(256, 3), 256, 0, stream>>>(X, Wbf, flags, Qb, Kb, Vb);
    vtrans<<<dim3(256, 4), 256, 0, stream>>>(Vb, VT);
    attn_part<<<dim3(NSPLIT, 64), 256, 0, stream>>>(Qb, Kb, VT, Mpk, Opart, lpart);
    combine<<<dim3(4096), 256, 0, stream>>>(Opart, lpart, out);
}